// Round 8
// baseline (212.559 us; speedup 1.0000x reference)
//
#include <hip/hip_runtime.h>

// Problem constants (match reference setup_inputs()).
#define Nn 50000
#define Rr 4
#define Dd 5
#define Ee 5000000
#define Bb 4
#define NRr (Nn * Rr)   // 200000
#define NDd (Nn * Dd)   // 250000
#define ZW 7814         // ceil(250000/32)=7813 (+1 guard word for ballot hi-write)
#define OUT_STRIDE (18 * Nn)
#define CSTR (Bb * NRr) // one i_rec copy: 800000 floats = 3.2 MB

struct P {
    const float* inputs; const float* z_buf; const float* v; const float* r;
    const float* asc1; const float* asc2; const float* psc_rise; const float* psc;
    const float* rec_w; const int* rec_rows; const int* rec_cols;
    const float* syn_decay; const float* psc_initial; const float* t_ref;
    const float* asc_amps; const float* k; const float* v_th; const float* e_l;
    const float* v_reset; const float* g; const float* decay;
    const float* current_factor; const float* vscale; const float* voffset;
    float* out; float* copies; unsigned char* z_pack; unsigned* zbits;
    int ncopies;
};

// ---------------------------------------------------------------------------
// Kernel 1: zero the i_rec copies (grid-stride), pack z_buf into per-column
// 4-bit batch masks + 1-bit OR mask (LDS-staged by edge kernel), and do the
// ENTIRE i_rec-independent neuron update (everything except new_psc_rise).
// Output layout per batch (18*N floats):
//   [0,N)=new_z [N,2N)=out_v [2N,3N)=new_r [3N,4N)=asc1 [4N,5N)=asc2
//   [5N,9N)=psc_rise(K3) [9N,13N)=psc [13N,18N)=shifted z_buf
// ---------------------------------------------------------------------------
__global__ __launch_bounds__(256) void pack_neuron_kernel(P p) {
    int i = blockIdx.x * 256 + threadIdx.x;
    int nthreads = gridDim.x * 256;

    // zero all copies
    int nz4 = p.ncopies * CSTR / 4;
    for (int t = i; t < nz4; t += nthreads)
        ((float4*)p.copies)[t] = make_float4(0.f, 0.f, 0.f, 0.f);

    // spike mask pack, domain NDd
    unsigned m = 0;
    if (i < NDd) {
#pragma unroll
        for (int b = 0; b < Bb; ++b)
            if (p.z_buf[(size_t)b * NDd + i] != 0.0f) m |= (1u << b);
        p.z_pack[i] = (unsigned char)m;
    }
    unsigned long long bal = __ballot(m != 0);
    if ((i & 63) == 0 && i < NDd) {
        p.zbits[(i >> 5)]     = (unsigned)bal;
        p.zbits[(i >> 5) + 1] = (unsigned)(bal >> 32);
    }

    // neuron update from old state, domain Bb*Nn
    if (i < Bb * Nn) {
        int b = i / Nn;
        int n = i - b * Nn;
        const size_t bn  = (size_t)b * Nn + n;
        const size_t bnr = (size_t)b * NRr + (size_t)n * 4;

        float prev_z = p.z_buf[(size_t)b * NDd + n];
        float4 pr = *(const float4*)(p.psc_rise + bnr);
        float4 pc = *(const float4*)(p.psc + bnr);
        float4 sd = *(const float4*)(p.syn_decay + (size_t)n * 4);

        float4 npc;
        npc.x = pc.x * sd.x + sd.x * pr.x;
        npc.y = pc.y * sd.y + sd.y * pr.y;
        npc.z = pc.z * sd.z + sd.z * pr.z;
        npc.w = pc.w * sd.w + sd.w * pr.w;
        float input_current = pc.x + pc.y + pc.z + pc.w;   // OLD psc

        float new_r = fmaxf(p.r[bn] + prev_z * p.t_ref[n] - 1.0f, 0.0f);

        float2 kv = *(const float2*)(p.k + (size_t)n * 2);
        float2 aa = *(const float2*)(p.asc_amps + (size_t)n * 2);
        float kk0 = 1.0f / (1.0f + expf(-kv.x));
        float kk1 = 1.0f / (1.0f + expf(-kv.y));
        float a1 = p.asc1[bn];
        float a2 = p.asc2[bn];
        float na1 = expf(-kk0) * a1 + prev_z * aa.x;
        float na2 = expf(-kk1) * a2 + prev_z * aa.y;

        float vth = p.v_th[n];
        float el  = p.e_l[n];
        float reset_current = prev_z * (p.v_reset[n] - vth);
        float c1 = input_current + a1 + a2 + p.g[n] * el;  // OLD asc
        float new_v = p.decay[n] * p.v[bn] + p.current_factor[n] * c1
                      + reset_current;
        float v_sc = (new_v - vth) / (vth - el);
        float new_z = (v_sc > 0.0f) ? 1.0f : 0.0f;
        if (new_r > 0.0f) new_z = 0.0f;
        float out_v = new_v * p.vscale[n] + p.voffset[n];

        float* ob = p.out + (size_t)b * OUT_STRIDE;
        ob[n]          = new_z;
        ob[Nn + n]     = out_v;
        ob[2 * Nn + n] = new_r;
        ob[3 * Nn + n] = na1;
        ob[4 * Nn + n] = na2;
        *(float4*)(ob + 9 * Nn + (size_t)n * 4) = npc;
        ob[13 * Nn + n] = new_z;
#pragma unroll
        for (int d = 0; d < Dd - 1; ++d)
            ob[14 * Nn + (size_t)d * Nn + n] =
                p.z_buf[(size_t)b * NDd + (size_t)d * Nn + n];
    }
}

// ---------------------------------------------------------------------------
// Kernel 2: edge scatter into the XCD-PRIVATE i_rec copy with relaxed
// workgroup-scope atomics (execute at the local XCD L2 -> no device
// coherence-point serialization). Each copy is only touched by workgroups
// on that XCD (s_getreg XCC_ID, HW-verified 0..7); end-of-dispatch system
// release makes all copies visible to kernel 3.
// ncopies==1 fallback: device-scope atomicAdd into copy 0 (always correct).
// ---------------------------------------------------------------------------
__global__ __launch_bounds__(256) void edge_kernel(P p) {
    __shared__ unsigned zb[ZW];
    for (int t = threadIdx.x; t < ZW; t += 256) zb[t] = p.zbits[t];
    __syncthreads();
    const int tid = blockIdx.x * 256 + threadIdx.x;
    if (tid >= Ee / 4) return;

    float* my;
    bool priv = (p.ncopies == 8);
    if (priv) {
        unsigned xcc;
        asm volatile("s_getreg_b32 %0, hwreg(HW_REG_XCC_ID)" : "=s"(xcc));
        my = p.copies + (size_t)(xcc & 7u) * CSTR;
    } else {
        my = p.copies;
    }

    int4 c = ((const int4*)p.rec_cols)[tid];
    unsigned h0 = (zb[(unsigned)c.x >> 5] >> (c.x & 31)) & 1u;
    unsigned h1 = (zb[(unsigned)c.y >> 5] >> (c.y & 31)) & 1u;
    unsigned h2 = (zb[(unsigned)c.z >> 5] >> (c.z & 31)) & 1u;
    unsigned h3 = (zb[(unsigned)c.w >> 5] >> (c.w & 31)) & 1u;
    if (!(h0 | h1 | h2 | h3)) return;

    int4 rw = ((const int4*)p.rec_rows)[tid];
    float4 w = ((const float4*)p.rec_w)[tid];

    auto acc = [&](int idx, float wv) {
        if (priv)
            __hip_atomic_fetch_add(&my[idx], wv, __ATOMIC_RELAXED,
                                   __HIP_MEMORY_SCOPE_WORKGROUP);
        else
            atomicAdd(&my[idx], wv);
    };
    auto do_edge = [&](unsigned hh, int col, int row, float wv) {
        if (hh) {
            unsigned mm = p.z_pack[col];
            if (mm & 1u) acc(0 * NRr + row, wv);
            if (mm & 2u) acc(1 * NRr + row, wv);
            if (mm & 4u) acc(2 * NRr + row, wv);
            if (mm & 8u) acc(3 * NRr + row, wv);
        }
    };
    do_edge(h0, c.x, rw.x, w.x);
    do_edge(h1, c.y, rw.y, w.y);
    do_edge(h2, c.z, rw.z, w.z);
    do_edge(h3, c.w, rw.w, w.w);
}

// ---------------------------------------------------------------------------
// Kernel 3: reduce copies + psc_rise (the only i_rec consumer), exact
// reference formula: npr = sd*pr + (i_rec + inputs)*pi.
// ---------------------------------------------------------------------------
__global__ __launch_bounds__(256) void psc_rise_kernel(P p) {
    int tid = blockIdx.x * 256 + threadIdx.x;
    if (tid >= Bb * Nn) return;
    int b = tid / Nn;
    int n = tid - b * Nn;
    const size_t bnr = (size_t)b * NRr + (size_t)n * 4;

    float4 s = make_float4(0.f, 0.f, 0.f, 0.f);
    for (int c = 0; c < p.ncopies; ++c) {
        float4 t = *(const float4*)(p.copies + (size_t)c * CSTR + bnr);
        s.x += t.x; s.y += t.y; s.z += t.z; s.w += t.w;
    }
    float4 in4 = *(const float4*)(p.inputs + bnr);
    float4 pr  = *(const float4*)(p.psc_rise + bnr);
    float4 sd  = *(const float4*)(p.syn_decay + (size_t)n * 4);
    float4 pi  = *(const float4*)(p.psc_initial + (size_t)n * 4);
    float4 npr;
    npr.x = sd.x * pr.x + (s.x + in4.x) * pi.x;
    npr.y = sd.y * pr.y + (s.y + in4.y) * pi.y;
    npr.z = sd.z * pr.z + (s.z + in4.z) * pi.z;
    npr.w = sd.w * pr.w + (s.w + in4.w) * pi.w;
    float* ob = p.out + (size_t)b * OUT_STRIDE;
    *(float4*)(ob + 5 * Nn + (size_t)n * 4) = npr;
}

extern "C" void kernel_launch(void* const* d_in, const int* in_sizes, int n_in,
                              void* d_out, int out_size, void* d_ws, size_t ws_size,
                              hipStream_t stream) {
    P p;
    p.inputs        = (const float*)d_in[0];
    p.z_buf         = (const float*)d_in[1];
    p.v             = (const float*)d_in[2];
    p.r             = (const float*)d_in[3];
    p.asc1          = (const float*)d_in[4];
    p.asc2          = (const float*)d_in[5];
    p.psc_rise      = (const float*)d_in[6];
    p.psc           = (const float*)d_in[7];
    p.rec_w         = (const float*)d_in[8];
    p.rec_rows      = (const int*)d_in[9];
    p.rec_cols      = (const int*)d_in[10];
    p.syn_decay     = (const float*)d_in[11];
    p.psc_initial   = (const float*)d_in[12];
    p.t_ref         = (const float*)d_in[13];
    p.asc_amps      = (const float*)d_in[14];
    p.k             = (const float*)d_in[15];
    p.v_th          = (const float*)d_in[16];
    p.e_l           = (const float*)d_in[17];
    p.v_reset       = (const float*)d_in[18];
    p.g             = (const float*)d_in[19];
    p.decay         = (const float*)d_in[20];
    p.current_factor= (const float*)d_in[21];
    p.vscale        = (const float*)d_in[22];
    p.voffset       = (const float*)d_in[23];
    p.out           = (float*)d_out;

    // Workspace: copies f32[ncopies*CSTR] @0 | z_pack u8[250k] | zbits u32[ZW]
    const size_t need8 = (size_t)8 * CSTR * 4 + 250112 + 4 * ZW;
    p.ncopies = (ws_size >= need8) ? 8 : 1;
    p.copies  = (float*)d_ws;
    p.z_pack  = (unsigned char*)d_ws + (size_t)p.ncopies * CSTR * 4;
    p.zbits   = (unsigned*)((char*)p.z_pack + 250112);

    pack_neuron_kernel<<<(NDd + 255) / 256, 256, 0, stream>>>(p);
    edge_kernel<<<(Ee / 4 + 255) / 256, 256, 0, stream>>>(p);
    psc_rise_kernel<<<(Bb * Nn + 255) / 256, 256, 0, stream>>>(p);
}

// Round 9
// 208.559 us; speedup vs baseline: 1.0192x; 1.0192x over previous
//
#include <hip/hip_runtime.h>

// Problem constants (match reference setup_inputs()).
#define Nn 50000
#define Rr 4
#define Dd 5
#define Ee 5000000
#define Bb 4
#define NRr (Nn * Rr)   // 200000
#define NDd (Nn * Dd)   // 250000
#define OUT_STRIDE (18 * Nn)

typedef int   v4i __attribute__((ext_vector_type(4)));
typedef float v4f __attribute__((ext_vector_type(4)));

struct P {
    const float* inputs; const float* z_buf; const float* v; const float* r;
    const float* asc1; const float* asc2; const float* psc_rise; const float* psc;
    const float* rec_w; const int* rec_rows; const int* rec_cols;
    const float* syn_decay; const float* psc_initial; const float* t_ref;
    const float* asc_amps; const float* k; const float* v_th; const float* e_l;
    const float* v_reset; const float* g; const float* decay;
    const float* current_factor; const float* vscale; const float* voffset;
    float* out; float* i_rec; unsigned char* z_pack;
};

// ---------------------------------------------------------------------------
// Kernel 1: zero i_rec, pack z_buf into per-column 4-bit batch masks
// (250 KB, stays L2-resident in K2 because the edge streams are NT there),
// and the ENTIRE i_rec-independent neuron update (all outputs except
// new_psc_rise). Output layout per batch (18*N floats):
//   [0,N)=new_z [N,2N)=out_v [2N,3N)=new_r [3N,4N)=asc1 [4N,5N)=asc2
//   [5N,9N)=psc_rise(K3) [9N,13N)=psc [13N,18N)=shifted z_buf
// ---------------------------------------------------------------------------
__global__ __launch_bounds__(256) void pack_neuron_kernel(P p) {
    int i = blockIdx.x * 256 + threadIdx.x;

    // zero i_rec (800K floats = 200K float4; first 200K threads)
    if (i < Bb * NRr / 4)
        ((float4*)p.i_rec)[i] = make_float4(0.f, 0.f, 0.f, 0.f);

    // spike mask pack, domain NDd
    if (i < NDd) {
        unsigned m = 0;
#pragma unroll
        for (int b = 0; b < Bb; ++b)
            if (p.z_buf[(size_t)b * NDd + i] != 0.0f) m |= (1u << b);
        p.z_pack[i] = (unsigned char)m;
    }

    // neuron update from old state, domain Bb*Nn
    if (i < Bb * Nn) {
        int b = i / Nn;
        int n = i - b * Nn;
        const size_t bn  = (size_t)b * Nn + n;
        const size_t bnr = (size_t)b * NRr + (size_t)n * 4;

        float prev_z = p.z_buf[(size_t)b * NDd + n];
        float4 pr = *(const float4*)(p.psc_rise + bnr);
        float4 pc = *(const float4*)(p.psc + bnr);
        float4 sd = *(const float4*)(p.syn_decay + (size_t)n * 4);

        float4 npc;
        npc.x = pc.x * sd.x + sd.x * pr.x;
        npc.y = pc.y * sd.y + sd.y * pr.y;
        npc.z = pc.z * sd.z + sd.z * pr.z;
        npc.w = pc.w * sd.w + sd.w * pr.w;
        float input_current = pc.x + pc.y + pc.z + pc.w;   // OLD psc

        float new_r = fmaxf(p.r[bn] + prev_z * p.t_ref[n] - 1.0f, 0.0f);

        float2 kv = *(const float2*)(p.k + (size_t)n * 2);
        float2 aa = *(const float2*)(p.asc_amps + (size_t)n * 2);
        float kk0 = 1.0f / (1.0f + expf(-kv.x));
        float kk1 = 1.0f / (1.0f + expf(-kv.y));
        float a1 = p.asc1[bn];
        float a2 = p.asc2[bn];
        float na1 = expf(-kk0) * a1 + prev_z * aa.x;
        float na2 = expf(-kk1) * a2 + prev_z * aa.y;

        float vth = p.v_th[n];
        float el  = p.e_l[n];
        float reset_current = prev_z * (p.v_reset[n] - vth);
        float c1 = input_current + a1 + a2 + p.g[n] * el;  // OLD asc
        float new_v = p.decay[n] * p.v[bn] + p.current_factor[n] * c1
                      + reset_current;
        float v_sc = (new_v - vth) / (vth - el);
        float new_z = (v_sc > 0.0f) ? 1.0f : 0.0f;
        if (new_r > 0.0f) new_z = 0.0f;
        float out_v = new_v * p.vscale[n] + p.voffset[n];

        float* ob = p.out + (size_t)b * OUT_STRIDE;
        ob[n]          = new_z;
        ob[Nn + n]     = out_v;
        ob[2 * Nn + n] = new_r;
        ob[3 * Nn + n] = na1;
        ob[4 * Nn + n] = na2;
        *(float4*)(ob + 9 * Nn + (size_t)n * 4) = npc;
        ob[13 * Nn + n] = new_z;
#pragma unroll
        for (int d = 0; d < Dd - 1; ++d)
            ob[14 * Nn + (size_t)d * Nn + n] =
                p.z_buf[(size_t)b * NDd + (size_t)d * Nn + n];
    }
}

// ---------------------------------------------------------------------------
// Kernel 2: edge scatter. The 60 MB cols/rows/w streams are read ONCE per
// call -> nontemporal (no L2 allocate) so they stop thrashing the 4 MB
// per-XCD L2. That keeps z_pack (250 KB) and i_rec (3.2 MB) L2-resident:
// the scattered gathers and atomics then run at L2 speed instead of paying
// a MALL/HBM round-trip per atomic (the R1..R8 ~60 us wall, fingerprinted
// by WRITE_SIZE ~= 1M x 32 B write-throughs). No LDS bitmask: R0 vs R1
// showed it neutral, and dropping its 31.7 KB restores ~68% occupancy to
// hide the NT loads' HBM latency.
// ---------------------------------------------------------------------------
__global__ __launch_bounds__(256) void edge_kernel(P p) {
    int tid = blockIdx.x * 256 + threadIdx.x;
    if (tid >= Ee / 4) return;

    v4i c = __builtin_nontemporal_load(&((const v4i*)p.rec_cols)[tid]);
    unsigned m0 = p.z_pack[c.x];
    unsigned m1 = p.z_pack[c.y];
    unsigned m2 = p.z_pack[c.z];
    unsigned m3 = p.z_pack[c.w];
    if (!(m0 | m1 | m2 | m3)) return;

    v4i rw = __builtin_nontemporal_load(&((const v4i*)p.rec_rows)[tid]);
    v4f w  = __builtin_nontemporal_load(&((const v4f*)p.rec_w)[tid]);
    float* i_rec = p.i_rec;
    auto do_edge = [&](unsigned mm, int row, float wv) {
        if (mm & 1u) atomicAdd(&i_rec[0 * NRr + row], wv);
        if (mm & 2u) atomicAdd(&i_rec[1 * NRr + row], wv);
        if (mm & 4u) atomicAdd(&i_rec[2 * NRr + row], wv);
        if (mm & 8u) atomicAdd(&i_rec[3 * NRr + row], wv);
    };
    do_edge(m0, rw.x, w.x);
    do_edge(m1, rw.y, w.y);
    do_edge(m2, rw.z, w.z);
    do_edge(m3, rw.w, w.w);
}

// ---------------------------------------------------------------------------
// Kernel 3: the only i_rec consumer: npr = sd*pr + (i_rec + inputs)*pi.
// ---------------------------------------------------------------------------
__global__ __launch_bounds__(256) void psc_rise_kernel(P p) {
    int tid = blockIdx.x * 256 + threadIdx.x;
    if (tid >= Bb * Nn) return;
    int b = tid / Nn;
    int n = tid - b * Nn;
    const size_t bnr = (size_t)b * NRr + (size_t)n * 4;
    float4 ir  = *(const float4*)(p.i_rec + bnr);
    float4 in4 = *(const float4*)(p.inputs + bnr);
    float4 pr  = *(const float4*)(p.psc_rise + bnr);
    float4 sd  = *(const float4*)(p.syn_decay + (size_t)n * 4);
    float4 pi  = *(const float4*)(p.psc_initial + (size_t)n * 4);
    float4 npr;
    npr.x = sd.x * pr.x + (ir.x + in4.x) * pi.x;
    npr.y = sd.y * pr.y + (ir.y + in4.y) * pi.y;
    npr.z = sd.z * pr.z + (ir.z + in4.z) * pi.z;
    npr.w = sd.w * pr.w + (ir.w + in4.w) * pi.w;
    float* ob = p.out + (size_t)b * OUT_STRIDE;
    *(float4*)(ob + 5 * Nn + (size_t)n * 4) = npr;
}

extern "C" void kernel_launch(void* const* d_in, const int* in_sizes, int n_in,
                              void* d_out, int out_size, void* d_ws, size_t ws_size,
                              hipStream_t stream) {
    P p;
    p.inputs        = (const float*)d_in[0];
    p.z_buf         = (const float*)d_in[1];
    p.v             = (const float*)d_in[2];
    p.r             = (const float*)d_in[3];
    p.asc1          = (const float*)d_in[4];
    p.asc2          = (const float*)d_in[5];
    p.psc_rise      = (const float*)d_in[6];
    p.psc           = (const float*)d_in[7];
    p.rec_w         = (const float*)d_in[8];
    p.rec_rows      = (const int*)d_in[9];
    p.rec_cols      = (const int*)d_in[10];
    p.syn_decay     = (const float*)d_in[11];
    p.psc_initial   = (const float*)d_in[12];
    p.t_ref         = (const float*)d_in[13];
    p.asc_amps      = (const float*)d_in[14];
    p.k             = (const float*)d_in[15];
    p.v_th          = (const float*)d_in[16];
    p.e_l           = (const float*)d_in[17];
    p.v_reset       = (const float*)d_in[18];
    p.g             = (const float*)d_in[19];
    p.decay         = (const float*)d_in[20];
    p.current_factor= (const float*)d_in[21];
    p.vscale        = (const float*)d_in[22];
    p.voffset       = (const float*)d_in[23];
    p.out           = (float*)d_out;

    // Workspace: i_rec f32[800k] @0 (3.2 MB) | z_pack u8[250k] @3,200,000
    p.i_rec  = (float*)d_ws;
    p.z_pack = (unsigned char*)d_ws + 3200000;

    pack_neuron_kernel<<<(NDd + 255) / 256, 256, 0, stream>>>(p);
    edge_kernel<<<(Ee / 4 + 255) / 256, 256, 0, stream>>>(p);
    psc_rise_kernel<<<(Bb * Nn + 255) / 256, 256, 0, stream>>>(p);
}